// Round 4
// baseline (267.543 us; speedup 1.0000x reference)
//
#include <hip/hip_runtime.h>
#include <hip/hip_cooperative_groups.h>
#include <math.h>

namespace cg = cooperative_groups;

// ---------------- problem constants ----------------
#define NS 3000          // 30*100 samples
#define NF 147           // 3*7*7 encoder feats
#define ND 512
#define NSIG 49          // 7x7 shift classes
#define NSAMP 12         // samples per P2 block-unit
#define NHBLK 250        // 3000 / 12
#define GSTRIDE 7232     // padded 3*2401
#define NRED 8           // fan-in groups for G partial reduction

// ---------------- ws layout (float offsets) ----------------
#define OFF_WT     0            // 6272 floats (7*224*4, float4-packed)
#define OFF_FEATS  6272         // 160
#define OFF_V      6432         // 7*3*224*49 = 230496
#define OFF_T      236928       // T2[sig][g][f]: 49*49*147 = 352947 (pad)
#define OFF_G      589952       // 7232
#define OFF_GP     597184       // 250*7232 = 1808000
// end = 2405184 floats = 9.62 MB

// weight of upsample(+reflect,+shift): output pixel p, shift sigma
__device__ __forceinline__ void wt_compute(int sigma, int p, int& i0c, int& i1c,
                                           float& w0, float& w1) {
  int k = p + sigma - 3;
  int r = k < 0 ? -k : (k > 223 ? 446 - k : k);    // np.pad 'reflect'
  float tc = (float)(2 * r - 31) * (1.0f / 64.0f); // (r+0.5)/32 - 0.5, exact
  float fl = floorf(tc);
  int i0 = (int)fl;
  float fr = tc - fl;
  i0c = min(max(i0, 0), 6);
  i1c = min(max(i0 + 1, 0), 6);
  w0 = 1.0f - fr;
  w1 = fr;
}

// single cooperative kernel: 256 blocks x 256 threads, 4 grid syncs
__global__ void __launch_bounds__(256) k_mega(const float* __restrict__ x,
                                              const float* __restrict__ Wenc,
                                              const float* __restrict__ grids,
                                              const int* __restrict__ shx,
                                              const int* __restrict__ shy,
                                              float* __restrict__ ws,
                                              float* __restrict__ out) {
  cg::grid_group grid = cg::this_grid();
  __shared__ __align__(16) float smem[9856];   // 39.4 KB, unioned across phases
  int t = threadIdx.x;
  int b = blockIdx.x;
  const int gsz = 256;

  // ================= P0: h_star feats + WT table + V =================
  for (int unit = b; unit < 277; unit += gsz) {
    if (unit < NF) {
      int c = unit / 49, rem = unit % 49, cy = rem / 7, cx = rem % 7;
      float acc = 0.f;
      for (int idx = t; idx < 1024; idx += 256) {
        int yy = idx >> 5, xx = idx & 31;
        acc += x[(c * 224 + cy * 32 + yy) * 224 + cx * 32 + xx];
      }
      for (int off = 32; off; off >>= 1) acc += __shfl_down(acc, off);
      if ((t & 63) == 0) smem[t >> 6] = acc;
      __syncthreads();
      if (t == 0)
        ws[OFF_FEATS + unit] = (smem[0] + smem[1] + smem[2] + smem[3]) * (1.0f / 1024.0f);
      __syncthreads();
    } else if (unit == NF) {
      float4* WT = (float4*)(ws + OFF_WT);
      for (int e = t; e < 7 * 224; e += 256) {
        int sigma = e / 224, p = e % 224;
        int i0c, i1c; float w0, w1;
        wt_compute(sigma, p, i0c, i1c, w0, w1);
        WT[e] = make_float4(w0, w1, __int_as_float(i0c), __int_as_float(i1c));
      }
    } else {
      int tid = (unit - NF - 1) * 256 + t;
      if (tid < 7 * 3 * 224 * 7) {
        int cx = tid % 7;
        int y  = (tid / 7) % 224;
        int c  = (tid / (7 * 224)) % 3;
        int sy = tid / (7 * 224 * 3);
        float acc[7];
        #pragma unroll
        for (int g = 0; g < 7; ++g) acc[g] = 0.f;
        const float* xrow = x + (c * 224 + y) * 224;
        for (int x0 = 0; x0 < 32; ++x0) {
          int px = cx * 32 + x0;
          int i0, i1; float w0, w1;
          wt_compute(sy, px, i0, i1, w0, w1);
          float v = xrow[px];
          #pragma unroll
          for (int g = 0; g < 7; ++g) {
            float w = (g == i0 ? w0 : 0.f) + (g == i1 ? w1 : 0.f);
            acc[g] = fmaf(w, v, acc[g]);
          }
        }
        float* Vp = ws + OFF_V + (((sy * 3 + c) * 224 + y) * 49 + cx * 7);
        #pragma unroll
        for (int g = 0; g < 7; ++g) Vp[g] = acc[g];
      }
    }
  }
  grid.sync();   // V, WT, feats ready

  // ================= P1: T2[sig][g][f] (coalesced stores) + zero G ========
  {
    const float4* WT = (const float4*)(ws + OFF_WT);
    for (int idx = b * 256 + t; idx < NSIG * 49 * NF; idx += gsz * 256) {
      int f = idx % NF;
      int gq = idx / NF;
      int g = gq % 49;
      int sig = gq / 49;
      int sx = sig / 7, sy = sig % 7;
      int gy = g / 7, gx = g % 7;
      int c = f / 49, rem = f % 49, cy = rem / 7, cx = rem % 7;
      const float* V = ws + OFF_V + ((sy * 3 + c) * 224) * 49 + cx * 7 + gx;
      float acc = 0.f;
      for (int y0 = 0; y0 < 32; ++y0) {
        int y = cy * 32 + y0;
        float4 wt = WT[sx * 224 + y];
        int i0 = __float_as_int(wt.z), i1 = __float_as_int(wt.w);
        float w = (gy == i0 ? wt.x : 0.f) + (gy == i1 ? wt.y : 0.f);
        acc = fmaf(w, V[y * 49], acc);
      }
      ws[OFF_T + idx] = acc * (1.0f / 1024.0f);
    }
    for (int e = b * 256 + t; e < GSTRIDE; e += gsz * 256) ws[OFF_G + e] = 0.f;
  }
  grid.sync();   // T2 ready, G zeroed

  // ================= P2: F = T2@g, H = F@Wenc, cos sims, LDS G-partials ====
  if (b < NHBLK) {
    float* sF    = smem;                 // 1764  [f][r]
    float* sGr   = smem + 1764;          // 588   [r][g]
    float* sFeat = smem + 2352;          // 148
    int*   sSig  = (int*)(smem + 2500);  // 12
    float* sS    = smem + 2512;          // 16
    float* sRed  = smem + 2528;          // 96  [2][12][4]
    float* sRedH = smem + 2624;          // 4
    float* sG    = smem + 2628;          // 7203
    int i0s = b * NSAMP;
    for (int e = t; e < NSAMP * 49; e += 256) sGr[e] = grids[i0s * 49 + e];
    if (t < NSAMP) sSig[t] = shx[i0s + t] * 7 + shy[i0s + t];
    if (t < NF) sFeat[t] = ws[OFF_FEATS + t];
    for (int e = t; e < 3 * 2401; e += 256) sG[e] = 0.f;
    __syncthreads();
    for (int idx = t; idx < NF * NSAMP; idx += 256) {
      int r = idx / NF, f = idx - r * NF;
      const float* T2 = ws + OFF_T + sSig[r] * (49 * NF) + f;
      const float* gr = sGr + r * 49;
      float acc = 0.f;
      #pragma unroll
      for (int g = 0; g < 49; ++g) acc = fmaf(T2[g * NF], gr[g], acc);
      sF[f * NSAMP + r] = acc;
    }
    __syncthreads();
    float accA[NSAMP], accB[NSAMP];
    #pragma unroll
    for (int r = 0; r < NSAMP; ++r) { accA[r] = 0.f; accB[r] = 0.f; }
    float h0 = 0.f, h1 = 0.f;
    const float* W0 = Wenc + t;
    const float* W1 = Wenc + t + 256;
    const float4* sF4 = (const float4*)sF;
    for (int f = 0; f < NF; ++f) {
      float w0 = W0[f * ND];
      float w1 = W1[f * ND];
      float fe = sFeat[f];
      h0 = fmaf(fe, w0, h0);
      h1 = fmaf(fe, w1, h1);
      float4 a0 = sF4[f * 3], a1 = sF4[f * 3 + 1], a2 = sF4[f * 3 + 2];
      float a[NSAMP] = {a0.x, a0.y, a0.z, a0.w, a1.x, a1.y, a1.z, a1.w,
                        a2.x, a2.y, a2.z, a2.w};
      #pragma unroll
      for (int r = 0; r < NSAMP; ++r) {
        accA[r] = fmaf(a[r], w0, accA[r]);
        accB[r] = fmaf(a[r], w1, accB[r]);
      }
    }
    int wave = t >> 6, lane = t & 63;
    float hq = h0 * h0 + h1 * h1;
    for (int off = 32; off; off >>= 1) hq += __shfl_down(hq, off);
    if (lane == 0) sRedH[wave] = hq;
    #pragma unroll
    for (int r = 0; r < NSAMP; ++r) {
      float np = accA[r] * h0 + accB[r] * h1;
      float sp = accA[r] * accA[r] + accB[r] * accB[r];
      for (int off = 32; off; off >>= 1) {
        np += __shfl_down(np, off);
        sp += __shfl_down(sp, off);
      }
      if (lane == 0) { sRed[(0 * NSAMP + r) * 4 + wave] = np;
                       sRed[(1 * NSAMP + r) * 4 + wave] = sp; }
    }
    __syncthreads();
    if (t == 0) sRedH[0] = sqrtf(sRedH[0] + sRedH[1] + sRedH[2] + sRedH[3]);
    __syncthreads();
    if (t < NSAMP) {
      float np = sRed[t * 4] + sRed[t * 4 + 1] + sRed[t * 4 + 2] + sRed[t * 4 + 3];
      float sp = sRed[(NSAMP + t) * 4] + sRed[(NSAMP + t) * 4 + 1] +
                 sRed[(NSAMP + t) * 4 + 2] + sRed[(NSAMP + t) * 4 + 3];
      float den = fmaxf(sRedH[0] * sqrtf(sp), 1e-8f);
      sS[t] = np / den;
    }
    __syncthreads();
    if (t < 3 * 49) {
      int p = t / 49, k = t - p * 49;
      #pragma unroll
      for (int r = 0; r < NSAMP; ++r) {
        if (sGr[r * 49 + k] != 0.f) {
          float s = sS[r];
          float add = (p == 0) ? 1.f : ((p == 1) ? s : s * s);
          sG[p * 2401 + sSig[r] * 49 + k] += add;   // thread owns (p,k): race-free
        }
      }
    }
    __syncthreads();
    float* P = ws + OFF_GP + b * GSTRIDE;
    for (int e = t; e < 3 * 2401; e += 256) P[e] = sG[e];
  }
  grid.sync();   // all 250 G-partials ready

  // ================= P3: 8-way partial reduction + atomic into G ==========
  {
    int gtid = b * 256 + t;
    if (gtid < 7203 * NRED) {
      int c = gtid / 7203;
      int e = gtid - c * 7203;
      int b0 = c * 32, b1 = min(NHBLK, b0 + 32);
      float acc = 0.f;
      for (int p = b0; p < b1; ++p) acc += ws[OFF_GP + p * GSTRIDE + e];
      atomicAdd(&ws[OFF_G + e], acc);
    }
  }
  grid.sync();   // G complete

  // ================= P4: per-px-column C slice + final Welford output =====
  if (b < 224) {
    float* Gl = smem;            // 7203
    float* sC = smem + 7232;     // 147  [k][sx][gy]
    for (int e = t; e < 3 * 2401; e += 256) Gl[e] = ws[OFF_G + e];
    __syncthreads();
    const float4* WT = (const float4*)(ws + OFF_WT);
    if (t < NF) {
      int k = t / 49, r = t - k * 49;
      int sx = r / 7, gy = r % 7;
      float acc = 0.f;
      for (int sy = 0; sy < 7; ++sy) {
        float4 wt = WT[sy * 224 + b];
        int i0 = __float_as_int(wt.z), i1 = __float_as_int(wt.w);
        int base = k * 2401 + (sx * 7 + sy) * 49 + gy * 7;
        acc += wt.x * Gl[base + i0] + wt.y * Gl[base + i1];
      }
      sC[t] = acc;
    }
    __syncthreads();
    if (t < 224) {
      int py = t;
      float S0 = 0.f, S1 = 0.f, S2 = 0.f;
      for (int sx = 0; sx < 7; ++sx) {
        float4 wt = WT[sx * 224 + py];
        int i0 = __float_as_int(wt.z), i1 = __float_as_int(wt.w);
        int base = sx * 7;
        S0 += wt.x * sC[base + i0]      + wt.y * sC[base + i1];
        S1 += wt.x * sC[49 + base + i0] + wt.y * sC[49 + base + i1];
        S2 += wt.x * sC[98 + base + i0] + wt.y * sC[98 + base + i1];
      }
      float W = 1e-10f + S0;
      float R = S1 / W;
      float U = S2 - S1 * S1 / W;
      out[py * 224 + b] = R;
      out[224 * 224 + py * 224 + b] = U / (W - 1.0f);
    }
  }
}

extern "C" void kernel_launch(void* const* d_in, const int* in_sizes, int n_in,
                              void* d_out, int out_size, void* d_ws, size_t ws_size,
                              hipStream_t stream) {
  const float* x     = (const float*)d_in[0];
  const float* Wenc  = (const float*)d_in[1];
  const float* grids = (const float*)d_in[2];
  const int*   shx   = (const int*)d_in[3];
  const int*   shy   = (const int*)d_in[4];
  float* out = (float*)d_out;
  float* ws  = (float*)d_ws;

  void* args[] = {(void*)&x, (void*)&Wenc, (void*)&grids, (void*)&shx,
                  (void*)&shy, (void*)&ws, (void*)&out};
  hipLaunchCooperativeKernel((void*)k_mega, dim3(256), dim3(256), args, 0, stream);
}

// Round 5
// 144.868 us; speedup vs baseline: 1.8468x; 1.8468x over previous
//
#include <hip/hip_runtime.h>
#include <math.h>

// ---------------- problem constants ----------------
#define NS 3000          // 30*100 samples
#define NF 147           // 3*7*7 encoder feats
#define ND 512
#define NSIG 49          // 7x7 shift classes
#define NSAMP 12         // samples per k_H2s block
#define NHBLK 250        // 3000 / 12
#define NGBLK 30         // k_G blocks (100 samples each)

// ---------------- ws layout (float offsets) ----------------
#define OFF_WT     0            // 6272 floats (7*224 float4: w0,w1,i0,i1)
#define OFF_FEATS  6272         // 160
#define OFF_V      6432         // 7*3*224*49 = 230496  -> ends 236928
#define OFF_T      236928       // T2[sig][g][f]: 49*49*147 = 352947 -> 589875
#define OFF_S      589952       // 3000 sims
#define OFF_G      593024       // 7203
// end < 600240 floats = 2.4 MB

// weight of upsample(+reflect,+shift): output pixel p, shift sigma
__device__ __forceinline__ void wt_compute(int sigma, int p, int& i0c, int& i1c,
                                           float& w0, float& w1) {
  int k = p + sigma - 3;
  int r = k < 0 ? -k : (k > 223 ? 446 - k : k);    // np.pad 'reflect'
  float tc = (float)(2 * r - 31) * (1.0f / 64.0f); // (r+0.5)/32 - 0.5, exact
  float fl = floorf(tc);
  int i0 = (int)fl;
  float fr = tc - fl;
  i0c = min(max(i0, 0), 6);
  i1c = min(max(i0 + 1, 0), 6);
  w0 = 1.0f - fr;
  w1 = fr;
}

// blocks 0..146: h_star feats (32x32 block means); 147: WT table; 148+: V
__global__ void __launch_bounds__(256) k_initV(const float* __restrict__ x,
                                               float* __restrict__ ws) {
  int b = blockIdx.x;
  int t = threadIdx.x;
  if (b < NF) {
    int c = b / 49, rem = b % 49, cy = rem / 7, cx = rem % 7;
    float acc = 0.f;
    for (int idx = t; idx < 1024; idx += 256) {
      int yy = idx >> 5, xx = idx & 31;
      acc += x[(c * 224 + cy * 32 + yy) * 224 + cx * 32 + xx];
    }
    for (int off = 32; off; off >>= 1) acc += __shfl_down(acc, off);
    __shared__ float red[4];
    int wave = t >> 6, lane = t & 63;
    if (lane == 0) red[wave] = acc;
    __syncthreads();
    if (t == 0) ws[OFF_FEATS + b] = (red[0] + red[1] + red[2] + red[3]) * (1.0f / 1024.0f);
  } else if (b == NF) {
    float4* WT = (float4*)(ws + OFF_WT);
    for (int e = t; e < 7 * 224; e += 256) {
      int sigma = e / 224, p = e % 224;
      int i0c, i1c; float w0, w1;
      wt_compute(sigma, p, i0c, i1c, w0, w1);
      WT[e] = make_float4(w0, w1, __int_as_float(i0c), __int_as_float(i1c));
    }
  } else {
    int tid = (b - NF - 1) * 256 + t;
    if (tid >= 7 * 3 * 224 * 7) return;
    int cx = tid % 7;
    int y  = (tid / 7) % 224;
    int c  = (tid / (7 * 224)) % 3;
    int sy = tid / (7 * 224 * 3);
    float acc[7];
    #pragma unroll
    for (int g = 0; g < 7; ++g) acc[g] = 0.f;
    const float* xrow = x + (c * 224 + y) * 224;
    for (int x0 = 0; x0 < 32; ++x0) {
      int px = cx * 32 + x0;
      int i0, i1; float w0, w1;
      wt_compute(sy, px, i0, i1, w0, w1);   // inline (no dep on WT block)
      float v = xrow[px];
      #pragma unroll
      for (int g = 0; g < 7; ++g) {
        float w = (g == i0 ? w0 : 0.f) + (g == i1 ? w1 : 0.f);
        acc[g] = fmaf(w, v, acc[g]);
      }
    }
    float* Vp = ws + OFF_V + (((sy * 3 + c) * 224 + y) * 49 + cx * 7);
    #pragma unroll
    for (int g = 0; g < 7; ++g) Vp[g] = acc[g];
  }
}

// T2[sig][g][c*49+cy*7+cx] from LDS-staged V slice; one block per (sig,c)
__global__ void __launch_bounds__(256) k_T2(float* __restrict__ ws) {
  __shared__ float sV[224 * 49];       // contiguous V[sy][c] slice, 43.9 KB
  __shared__ float4 sWT[224];          // y-axis weights for sx
  int b = blockIdx.x;
  int sig = b / 3, c = b % 3;
  int sx = sig / 7, sy = sig % 7;
  int t = threadIdx.x;
  const float* Vsl = ws + OFF_V + ((sy * 3 + c) * 224) * 49;
  for (int e = t; e < 224 * 49; e += 256) sV[e] = Vsl[e];
  const float4* WT = (const float4*)(ws + OFF_WT);
  for (int e = t; e < 224; e += 256) sWT[e] = WT[sx * 224 + e];
  __syncthreads();
  for (int idx = t; idx < 49 * 49; idx += 256) {
    int g = idx / 49, rem = idx - g * 49;
    int gy = g / 7, gx = g % 7;
    int cy = rem / 7, cx = rem % 7;
    const float* vb = sV + cx * 7 + gx;
    float acc = 0.f;
    #pragma unroll 8
    for (int y0 = 0; y0 < 32; ++y0) {
      int y = cy * 32 + y0;
      float4 wt = sWT[y];
      int i0 = __float_as_int(wt.z), i1 = __float_as_int(wt.w);
      float w = (gy == i0 ? wt.x : 0.f) + (gy == i1 ? wt.y : 0.f);
      acc = fmaf(w, vb[y * 49], acc);
    }
    ws[OFF_T + (sig * 49 + g) * NF + c * 49 + rem] = acc * (1.0f / 1024.0f);
  }
}

// fused: F = T2[sig]@g (LDS), h* col + H = F@Wenc one pass, s_i out; zero G
__global__ void __launch_bounds__(256) k_H2s(const float* __restrict__ Wenc,
                                             const float* __restrict__ grids,
                                             const int* __restrict__ shx,
                                             const int* __restrict__ shy,
                                             float* __restrict__ ws) {
  __shared__ __align__(16) float sF[NF * NSAMP];  // [f][r]
  __shared__ float sGr[NSAMP * 49];               // [r][g]
  __shared__ float sFeat[NF];
  __shared__ int   sSig[NSAMP];
  __shared__ float sRed[2][NSAMP][4];
  __shared__ float sRedH[4];
  int t = threadIdx.x;
  int b = blockIdx.x;
  // zero G for k_G's atomics (blocks 0..28 cover 7203 elements)
  {
    int e = b * 256 + t;
    if (e < 7203) ws[OFF_G + e] = 0.f;
  }
  int i0s = b * NSAMP;
  for (int e = t; e < NSAMP * 49; e += 256) sGr[e] = grids[i0s * 49 + e];
  if (t < NSAMP) sSig[t] = shx[i0s + t] * 7 + shy[i0s + t];
  if (t < NF) sFeat[t] = ws[OFF_FEATS + t];
  __syncthreads();
  for (int idx = t; idx < NF * NSAMP; idx += 256) {
    int r = idx / NF, f = idx - r * NF;
    const float* T2 = ws + OFF_T + sSig[r] * (49 * NF) + f;
    const float* gr = sGr + r * 49;
    float acc = 0.f;
    #pragma unroll
    for (int g = 0; g < 49; ++g) acc = fmaf(T2[g * NF], gr[g], acc);
    sF[f * NSAMP + r] = acc;
  }
  __syncthreads();
  float accA[NSAMP], accB[NSAMP];
  #pragma unroll
  for (int r = 0; r < NSAMP; ++r) { accA[r] = 0.f; accB[r] = 0.f; }
  float h0 = 0.f, h1 = 0.f;
  const float* W0 = Wenc + t;
  const float* W1 = Wenc + t + 256;
  const float4* sF4 = (const float4*)sF;
  for (int f = 0; f < NF; ++f) {
    float w0 = W0[f * ND];
    float w1 = W1[f * ND];
    float fe = sFeat[f];
    h0 = fmaf(fe, w0, h0);
    h1 = fmaf(fe, w1, h1);
    float4 a0 = sF4[f * 3], a1 = sF4[f * 3 + 1], a2 = sF4[f * 3 + 2];
    float a[NSAMP] = {a0.x, a0.y, a0.z, a0.w, a1.x, a1.y, a1.z, a1.w,
                      a2.x, a2.y, a2.z, a2.w};
    #pragma unroll
    for (int r = 0; r < NSAMP; ++r) {
      accA[r] = fmaf(a[r], w0, accA[r]);
      accB[r] = fmaf(a[r], w1, accB[r]);
    }
  }
  int wave = t >> 6, lane = t & 63;
  float hq = h0 * h0 + h1 * h1;
  for (int off = 32; off; off >>= 1) hq += __shfl_down(hq, off);
  if (lane == 0) sRedH[wave] = hq;
  #pragma unroll
  for (int r = 0; r < NSAMP; ++r) {
    float np = accA[r] * h0 + accB[r] * h1;
    float sp = accA[r] * accA[r] + accB[r] * accB[r];
    for (int off = 32; off; off >>= 1) {
      np += __shfl_down(np, off);
      sp += __shfl_down(sp, off);
    }
    if (lane == 0) { sRed[0][r][wave] = np; sRed[1][r][wave] = sp; }
  }
  __syncthreads();
  if (t == 0) sRedH[0] = sqrtf(sRedH[0] + sRedH[1] + sRedH[2] + sRedH[3]);
  __syncthreads();
  if (t < NSAMP) {
    float np = sRed[0][t][0] + sRed[0][t][1] + sRed[0][t][2] + sRed[0][t][3];
    float sp = sRed[1][t][0] + sRed[1][t][1] + sRed[1][t][2] + sRed[1][t][3];
    float den = fmaxf(sRedH[0] * sqrtf(sp), 1e-8f);
    ws[OFF_S + i0s + t] = np / den;
  }
}

// per-block (p,k)-ownership accumulation of G over 100 samples, atomic merge
__global__ void __launch_bounds__(256) k_G(const float* __restrict__ grids,
                                           const int* __restrict__ shx,
                                           const int* __restrict__ shy,
                                           float* __restrict__ ws) {
  __shared__ float sG[3 * 2401];
  __shared__ float sGr[100 * 49];
  __shared__ float sS[100];
  __shared__ int   sSig[100];
  int b = blockIdx.x;
  int t = threadIdx.x;
  for (int e = t; e < 3 * 2401; e += 256) sG[e] = 0.f;
  for (int e = t; e < 100 * 49; e += 256) sGr[e] = grids[b * 4900 + e];
  if (t < 100) {
    sS[t] = ws[OFF_S + b * 100 + t];
    sSig[t] = shx[b * 100 + t] * 7 + shy[b * 100 + t];
  }
  __syncthreads();
  if (t < NF) {
    int p = t / 49, k = t - p * 49;
    for (int r = 0; r < 100; ++r) {
      float gv = sGr[r * 49 + k];
      if (gv != 0.f) {
        float s = sS[r];
        float add = (p == 0) ? 1.f : ((p == 1) ? s : s * s);
        sG[p * 2401 + sSig[r] * 49 + k] += add;   // thread owns (p,k): race-free
      }
    }
  }
  __syncthreads();
  for (int e = t; e < 3 * 2401; e += 256) atomicAdd(&ws[OFF_G + e], sG[e]);
}

// per-px-column C slice + final Welford output (one block per px)
__global__ void __launch_bounds__(256) k_CO(const float* __restrict__ ws,
                                            float* __restrict__ out) {
  __shared__ float Gl[3 * 2401];
  __shared__ float sC[NF];          // [k][sx][gy]
  int b = blockIdx.x;               // px
  int t = threadIdx.x;
  for (int e = t; e < 3 * 2401; e += 256) Gl[e] = ws[OFF_G + e];
  __syncthreads();
  const float4* WT = (const float4*)(ws + OFF_WT);
  if (t < NF) {
    int k = t / 49, r = t - k * 49;
    int sx = r / 7, gy = r % 7;
    float acc = 0.f;
    for (int sy = 0; sy < 7; ++sy) {
      float4 wt = WT[sy * 224 + b];
      int i0 = __float_as_int(wt.z), i1 = __float_as_int(wt.w);
      int base = k * 2401 + (sx * 7 + sy) * 49 + gy * 7;
      acc += wt.x * Gl[base + i0] + wt.y * Gl[base + i1];
    }
    sC[t] = acc;
  }
  __syncthreads();
  if (t < 224) {
    int py = t;
    float S0 = 0.f, S1 = 0.f, S2 = 0.f;
    for (int sx = 0; sx < 7; ++sx) {
      float4 wt = WT[sx * 224 + py];
      int i0 = __float_as_int(wt.z), i1 = __float_as_int(wt.w);
      int base = sx * 7;
      S0 += wt.x * sC[base + i0]      + wt.y * sC[base + i1];
      S1 += wt.x * sC[49 + base + i0] + wt.y * sC[49 + base + i1];
      S2 += wt.x * sC[98 + base + i0] + wt.y * sC[98 + base + i1];
    }
    float W = 1e-10f + S0;
    float R = S1 / W;
    float U = S2 - S1 * S1 / W;
    out[py * 224 + b] = R;
    out[224 * 224 + py * 224 + b] = U / (W - 1.0f);
  }
}

extern "C" void kernel_launch(void* const* d_in, const int* in_sizes, int n_in,
                              void* d_out, int out_size, void* d_ws, size_t ws_size,
                              hipStream_t stream) {
  const float* x     = (const float*)d_in[0];
  const float* Wenc  = (const float*)d_in[1];
  const float* grids = (const float*)d_in[2];
  const int*   shx   = (const int*)d_in[3];
  const int*   shy   = (const int*)d_in[4];
  float* out = (float*)d_out;
  float* ws  = (float*)d_ws;

  int vblocks = (7 * 3 * 224 * 7 + 255) / 256;           // 129
  k_initV<<<NF + 1 + vblocks, 256, 0, stream>>>(x, ws);  // 277 blocks
  k_T2<<<NSIG * 3, 256, 0, stream>>>(ws);                // 147 blocks
  k_H2s<<<NHBLK, 256, 0, stream>>>(Wenc, grids, shx, shy, ws);
  k_G<<<NGBLK, 256, 0, stream>>>(grids, shx, shy, ws);
  k_CO<<<224, 256, 0, stream>>>(ws, out);
}

// Round 6
// 133.334 us; speedup vs baseline: 2.0066x; 1.0865x over previous
//
#include <hip/hip_runtime.h>
#include <math.h>

// ---------------- problem constants ----------------
#define NS 3000          // 30*100 samples
#define NF 147           // 3*7*7 encoder feats
#define ND 512
#define NSIG 49          // 7x7 shift classes
#define NSAMP 12         // samples per k_H2s block
#define NHBLK 250        // 3000 / 12
#define NGBLK 30         // k_G blocks (100 samples each)

// ---------------- ws layout (float offsets) ----------------
#define OFF_WT     0            // 6272 floats (7*224 float4: w0,w1,i0,i1)
#define OFF_FEATS  6272         // 160
#define OFF_V      6432         // 7*3*224*49 = 230496  -> ends 236928
#define OFF_T      236928       // T2[sig][g][f]: 49*49*147 = 352947 -> 589875
#define OFF_S      589952       // 3000 sims
#define OFF_G      593024       // 7203
// end < 600240 floats = 2.4 MB

// weight of upsample(+reflect,+shift): output pixel p, shift sigma
__device__ __forceinline__ void wt_compute(int sigma, int p, int& i0c, int& i1c,
                                           float& w0, float& w1) {
  int k = p + sigma - 3;
  int r = k < 0 ? -k : (k > 223 ? 446 - k : k);    // np.pad 'reflect'
  float tc = (float)(2 * r - 31) * (1.0f / 64.0f); // (r+0.5)/32 - 0.5, exact
  float fl = floorf(tc);
  int i0 = (int)fl;
  float fr = tc - fl;
  i0c = min(max(i0, 0), 6);
  i1c = min(max(i0 + 1, 0), 6);
  w0 = 1.0f - fr;
  w1 = fr;
}

// blocks 0..146: h_star feats (32x32 block means); 147: WT table; 148+: V
__global__ void __launch_bounds__(256) k_initV(const float* __restrict__ x,
                                               float* __restrict__ ws) {
  int b = blockIdx.x;
  int t = threadIdx.x;
  if (b < NF) {
    int c = b / 49, rem = b % 49, cy = rem / 7, cx = rem % 7;
    float acc = 0.f;
    for (int idx = t; idx < 1024; idx += 256) {
      int yy = idx >> 5, xx = idx & 31;
      acc += x[(c * 224 + cy * 32 + yy) * 224 + cx * 32 + xx];
    }
    for (int off = 32; off; off >>= 1) acc += __shfl_down(acc, off);
    __shared__ float red[4];
    int wave = t >> 6, lane = t & 63;
    if (lane == 0) red[wave] = acc;
    __syncthreads();
    if (t == 0) ws[OFF_FEATS + b] = (red[0] + red[1] + red[2] + red[3]) * (1.0f / 1024.0f);
  } else if (b == NF) {
    float4* WT = (float4*)(ws + OFF_WT);
    for (int e = t; e < 7 * 224; e += 256) {
      int sigma = e / 224, p = e % 224;
      int i0c, i1c; float w0, w1;
      wt_compute(sigma, p, i0c, i1c, w0, w1);
      WT[e] = make_float4(w0, w1, __int_as_float(i0c), __int_as_float(i1c));
    }
  } else {
    int tid = (b - NF - 1) * 256 + t;
    if (tid >= 7 * 3 * 224 * 7) return;
    int cx = tid % 7;
    int y  = (tid / 7) % 224;
    int c  = (tid / (7 * 224)) % 3;
    int sy = tid / (7 * 224 * 3);
    float acc[7];
    #pragma unroll
    for (int g = 0; g < 7; ++g) acc[g] = 0.f;
    const float* xrow = x + (c * 224 + y) * 224;
    for (int x0 = 0; x0 < 32; ++x0) {
      int px = cx * 32 + x0;
      int i0, i1; float w0, w1;
      wt_compute(sy, px, i0, i1, w0, w1);   // inline (no dep on WT block)
      float v = xrow[px];
      #pragma unroll
      for (int g = 0; g < 7; ++g) {
        float w = (g == i0 ? w0 : 0.f) + (g == i1 ? w1 : 0.f);
        acc[g] = fmaf(w, v, acc[g]);
      }
    }
    float* Vp = ws + OFF_V + (((sy * 3 + c) * 224 + y) * 49 + cx * 7);
    #pragma unroll
    for (int g = 0; g < 7; ++g) Vp[g] = acc[g];
  }
}

// T2[sig][g][f] = (1/1024) sum_{y in cy-block} wy(y,gy;sx) * V[sy][c][y][cx][gx]
// R3-proven flat-parallel form (1379 blocks); transposed store for k_H2s.
__global__ void __launch_bounds__(256) k_T(float* __restrict__ ws) {
  int tid = blockIdx.x * blockDim.x + threadIdx.x;
  if (tid >= NSIG * NF * 49) return;
  int g = tid % 49;
  int f = (tid / 49) % NF;
  int sig = tid / (49 * NF);
  int sx = sig / 7, sy = sig % 7;
  int gy = g / 7, gx = g % 7;
  int c = f / 49, rem = f % 49, cy = rem / 7, cx = rem % 7;
  const float4* WT = (const float4*)(ws + OFF_WT);
  const float* V = ws + OFF_V + ((sy * 3 + c) * 224) * 49 + cx * 7 + gx;
  float acc = 0.f;
  for (int y0 = 0; y0 < 32; ++y0) {
    int y = cy * 32 + y0;
    float4 wt = WT[sx * 224 + y];
    int i0 = __float_as_int(wt.z), i1 = __float_as_int(wt.w);
    float w = (gy == i0 ? wt.x : 0.f) + (gy == i1 ? wt.y : 0.f);
    acc = fmaf(w, V[y * 49], acc);
  }
  ws[OFF_T + (sig * 49 + g) * NF + f] = acc * (1.0f / 1024.0f);
}

// fused: F = T2[sig]@g (LDS), h* col + H = F@Wenc one pass, s_i out; zero G
__global__ void __launch_bounds__(256) k_H2s(const float* __restrict__ Wenc,
                                             const float* __restrict__ grids,
                                             const int* __restrict__ shx,
                                             const int* __restrict__ shy,
                                             float* __restrict__ ws) {
  __shared__ __align__(16) float sF[NF * NSAMP];  // [f][r]
  __shared__ float sGr[NSAMP * 49];               // [r][g]
  __shared__ float sFeat[NF];
  __shared__ int   sSig[NSAMP];
  __shared__ float sRed[2][NSAMP][4];
  __shared__ float sRedH[4];
  int t = threadIdx.x;
  int b = blockIdx.x;
  // zero G for k_G's atomics (blocks 0..28 cover 7203 elements)
  {
    int e = b * 256 + t;
    if (e < 7203) ws[OFF_G + e] = 0.f;
  }
  int i0s = b * NSAMP;
  for (int e = t; e < NSAMP * 49; e += 256) sGr[e] = grids[i0s * 49 + e];
  if (t < NSAMP) sSig[t] = shx[i0s + t] * 7 + shy[i0s + t];
  if (t < NF) sFeat[t] = ws[OFF_FEATS + t];
  __syncthreads();
  for (int idx = t; idx < NF * NSAMP; idx += 256) {
    int r = idx / NF, f = idx - r * NF;
    const float* T2 = ws + OFF_T + sSig[r] * (49 * NF) + f;
    const float* gr = sGr + r * 49;
    float acc = 0.f;
    #pragma unroll
    for (int g = 0; g < 49; ++g) acc = fmaf(T2[g * NF], gr[g], acc);
    sF[f * NSAMP + r] = acc;
  }
  __syncthreads();
  float accA[NSAMP], accB[NSAMP];
  #pragma unroll
  for (int r = 0; r < NSAMP; ++r) { accA[r] = 0.f; accB[r] = 0.f; }
  float h0 = 0.f, h1 = 0.f;
  const float* W0 = Wenc + t;
  const float* W1 = Wenc + t + 256;
  const float4* sF4 = (const float4*)sF;
  for (int f = 0; f < NF; ++f) {
    float w0 = W0[f * ND];
    float w1 = W1[f * ND];
    float fe = sFeat[f];
    h0 = fmaf(fe, w0, h0);
    h1 = fmaf(fe, w1, h1);
    float4 a0 = sF4[f * 3], a1 = sF4[f * 3 + 1], a2 = sF4[f * 3 + 2];
    float a[NSAMP] = {a0.x, a0.y, a0.z, a0.w, a1.x, a1.y, a1.z, a1.w,
                      a2.x, a2.y, a2.z, a2.w};
    #pragma unroll
    for (int r = 0; r < NSAMP; ++r) {
      accA[r] = fmaf(a[r], w0, accA[r]);
      accB[r] = fmaf(a[r], w1, accB[r]);
    }
  }
  int wave = t >> 6, lane = t & 63;
  float hq = h0 * h0 + h1 * h1;
  for (int off = 32; off; off >>= 1) hq += __shfl_down(hq, off);
  if (lane == 0) sRedH[wave] = hq;
  #pragma unroll
  for (int r = 0; r < NSAMP; ++r) {
    float np = accA[r] * h0 + accB[r] * h1;
    float sp = accA[r] * accA[r] + accB[r] * accB[r];
    for (int off = 32; off; off >>= 1) {
      np += __shfl_down(np, off);
      sp += __shfl_down(sp, off);
    }
    if (lane == 0) { sRed[0][r][wave] = np; sRed[1][r][wave] = sp; }
  }
  __syncthreads();
  if (t == 0) sRedH[0] = sqrtf(sRedH[0] + sRedH[1] + sRedH[2] + sRedH[3]);
  __syncthreads();
  if (t < NSAMP) {
    float np = sRed[0][t][0] + sRed[0][t][1] + sRed[0][t][2] + sRed[0][t][3];
    float sp = sRed[1][t][0] + sRed[1][t][1] + sRed[1][t][2] + sRed[1][t][3];
    float den = fmaxf(sRedH[0] * sqrtf(sp), 1e-8f);
    ws[OFF_S + i0s + t] = np / den;
  }
}

// per-block (p,k)-ownership accumulation; 2 sample-groups of 50 to halve the
// serial LDS dependency chain; atomic merge into pre-zeroed G
__global__ void __launch_bounds__(512) k_G(const float* __restrict__ grids,
                                           const int* __restrict__ shx,
                                           const int* __restrict__ shy,
                                           float* __restrict__ ws) {
  __shared__ float sG[2][3 * 2401];   // 57.6 KB
  __shared__ float sGr[100 * 49];     // 19.6 KB
  __shared__ float sS[100];
  __shared__ int   sSig[100];
  int b = blockIdx.x;
  int t = threadIdx.x;
  for (int e = t; e < 2 * 3 * 2401; e += 512) ((float*)sG)[e] = 0.f;
  for (int e = t; e < 100 * 49; e += 512) sGr[e] = grids[b * 4900 + e];
  if (t < 100) {
    sS[t] = ws[OFF_S + b * 100 + t];
    sSig[t] = shx[b * 100 + t] * 7 + shy[b * 100 + t];
  }
  __syncthreads();
  int grp = t >> 8, u = t & 255;
  if (u < NF) {
    int p = u / 49, k = u - p * 49;
    float* dst = sG[grp] + p * 2401 + k;
    for (int r = grp * 50; r < grp * 50 + 50; ++r) {
      float gv = sGr[r * 49 + k];
      if (gv != 0.f) {
        float s = sS[r];
        float add = (p == 0) ? 1.f : ((p == 1) ? s : s * s);
        dst[sSig[r] * 49] += add;     // thread owns (grp,p,k): race-free
      }
    }
  }
  __syncthreads();
  for (int e = t; e < 3 * 2401; e += 512)
    atomicAdd(&ws[OFF_G + e], sG[0][e] + sG[1][e]);
}

// per-px-column C slice + final Welford output (one block per px)
__global__ void __launch_bounds__(256) k_CO(const float* __restrict__ ws,
                                            float* __restrict__ out) {
  __shared__ float Gl[3 * 2401];
  __shared__ float sC[NF];          // [k][sx][gy]
  int b = blockIdx.x;               // px
  int t = threadIdx.x;
  for (int e = t; e < 3 * 2401; e += 256) Gl[e] = ws[OFF_G + e];
  __syncthreads();
  const float4* WT = (const float4*)(ws + OFF_WT);
  if (t < NF) {
    int k = t / 49, r = t - k * 49;
    int sx = r / 7, gy = r % 7;
    float acc = 0.f;
    for (int sy = 0; sy < 7; ++sy) {
      float4 wt = WT[sy * 224 + b];
      int i0 = __float_as_int(wt.z), i1 = __float_as_int(wt.w);
      int base = k * 2401 + (sx * 7 + sy) * 49 + gy * 7;
      acc += wt.x * Gl[base + i0] + wt.y * Gl[base + i1];
    }
    sC[t] = acc;
  }
  __syncthreads();
  if (t < 224) {
    int py = t;
    float S0 = 0.f, S1 = 0.f, S2 = 0.f;
    for (int sx = 0; sx < 7; ++sx) {
      float4 wt = WT[sx * 224 + py];
      int i0 = __float_as_int(wt.z), i1 = __float_as_int(wt.w);
      int base = sx * 7;
      S0 += wt.x * sC[base + i0]      + wt.y * sC[base + i1];
      S1 += wt.x * sC[49 + base + i0] + wt.y * sC[49 + base + i1];
      S2 += wt.x * sC[98 + base + i0] + wt.y * sC[98 + base + i1];
    }
    float W = 1e-10f + S0;
    float R = S1 / W;
    float U = S2 - S1 * S1 / W;
    out[py * 224 + b] = R;
    out[224 * 224 + py * 224 + b] = U / (W - 1.0f);
  }
}

extern "C" void kernel_launch(void* const* d_in, const int* in_sizes, int n_in,
                              void* d_out, int out_size, void* d_ws, size_t ws_size,
                              hipStream_t stream) {
  const float* x     = (const float*)d_in[0];
  const float* Wenc  = (const float*)d_in[1];
  const float* grids = (const float*)d_in[2];
  const int*   shx   = (const int*)d_in[3];
  const int*   shy   = (const int*)d_in[4];
  float* out = (float*)d_out;
  float* ws  = (float*)d_ws;

  int vblocks = (7 * 3 * 224 * 7 + 255) / 256;           // 129
  k_initV<<<NF + 1 + vblocks, 256, 0, stream>>>(x, ws);  // 277 blocks
  k_T<<<(NSIG * NF * 49 + 255) / 256, 256, 0, stream>>>(ws);  // 1379 blocks
  k_H2s<<<NHBLK, 256, 0, stream>>>(Wenc, grids, shx, shy, ws);
  k_G<<<NGBLK, 512, 0, stream>>>(grids, shx, shy, ws);
  k_CO<<<224, 256, 0, stream>>>(ws, out);
}

// Round 7
// 121.621 us; speedup vs baseline: 2.1998x; 1.0963x over previous
//
#include <hip/hip_runtime.h>
#include <math.h>

// ---------------- problem constants ----------------
#define NS 3000          // 30*100 samples
#define NF 147           // 3*7*7 encoder feats
#define ND 512
#define NSIG 49          // 7x7 shift classes
#define NSAMP 12         // samples per k_H2s block
#define NHBLK 250        // 3000 / 12

// ---------------- ws layout (float offsets) ----------------
#define OFF_WT     0            // 6272 floats (7*224 float4: w0,w1,i0,i1)
#define OFF_FEATS  6272         // 160
#define OFF_V      6432         // 7*3*224*49 = 230496  -> ends 236928
#define OFF_T      236928       // T2[sig][g][f]: 49*49*147 = 352947 -> 589875
#define OFF_G      589952       // 7203
// end < 600240 floats = 2.4 MB

// weight of upsample(+reflect,+shift): output pixel p, shift sigma
__device__ __forceinline__ void wt_compute(int sigma, int p, int& i0c, int& i1c,
                                           float& w0, float& w1) {
  int k = p + sigma - 3;
  int r = k < 0 ? -k : (k > 223 ? 446 - k : k);    // np.pad 'reflect'
  float tc = (float)(2 * r - 31) * (1.0f / 64.0f); // (r+0.5)/32 - 0.5, exact
  float fl = floorf(tc);
  int i0 = (int)fl;
  float fr = tc - fl;
  i0c = min(max(i0, 0), 6);
  i1c = min(max(i0 + 1, 0), 6);
  w0 = 1.0f - fr;
  w1 = fr;
}

// blocks 0..146: h_star feats (32x32 block means); 147: WT table; 148+: V
__global__ void __launch_bounds__(256) k_initV(const float* __restrict__ x,
                                               float* __restrict__ ws) {
  int b = blockIdx.x;
  int t = threadIdx.x;
  if (b < NF) {
    int c = b / 49, rem = b % 49, cy = rem / 7, cx = rem % 7;
    float acc = 0.f;
    for (int idx = t; idx < 1024; idx += 256) {
      int yy = idx >> 5, xx = idx & 31;
      acc += x[(c * 224 + cy * 32 + yy) * 224 + cx * 32 + xx];
    }
    for (int off = 32; off; off >>= 1) acc += __shfl_down(acc, off);
    __shared__ float red[4];
    int wave = t >> 6, lane = t & 63;
    if (lane == 0) red[wave] = acc;
    __syncthreads();
    if (t == 0) ws[OFF_FEATS + b] = (red[0] + red[1] + red[2] + red[3]) * (1.0f / 1024.0f);
  } else if (b == NF) {
    float4* WT = (float4*)(ws + OFF_WT);
    for (int e = t; e < 7 * 224; e += 256) {
      int sigma = e / 224, p = e % 224;
      int i0c, i1c; float w0, w1;
      wt_compute(sigma, p, i0c, i1c, w0, w1);
      WT[e] = make_float4(w0, w1, __int_as_float(i0c), __int_as_float(i1c));
    }
  } else {
    int tid = (b - NF - 1) * 256 + t;
    if (tid >= 7 * 3 * 224 * 7) return;
    int cx = tid % 7;
    int y  = (tid / 7) % 224;
    int c  = (tid / (7 * 224)) % 3;
    int sy = tid / (7 * 224 * 3);
    float acc[7];
    #pragma unroll
    for (int g = 0; g < 7; ++g) acc[g] = 0.f;
    const float* xrow = x + (c * 224 + y) * 224;
    for (int x0 = 0; x0 < 32; ++x0) {
      int px = cx * 32 + x0;
      int i0, i1; float w0, w1;
      wt_compute(sy, px, i0, i1, w0, w1);   // inline (no dep on WT block)
      float v = xrow[px];
      #pragma unroll
      for (int g = 0; g < 7; ++g) {
        float w = (g == i0 ? w0 : 0.f) + (g == i1 ? w1 : 0.f);
        acc[g] = fmaf(w, v, acc[g]);
      }
    }
    float* Vp = ws + OFF_V + (((sy * 3 + c) * 224 + y) * 49 + cx * 7);
    #pragma unroll
    for (int g = 0; g < 7; ++g) Vp[g] = acc[g];
  }
}

// T2[sig][g][f] = (1/1024) sum_{y in cy-block} wy(y,gy;sx) * V[sy][c][y][cx][gx]
// tail threads zero G for k_H2s's atomics
__global__ void __launch_bounds__(256) k_T(float* __restrict__ ws) {
  int tid = blockIdx.x * blockDim.x + threadIdx.x;
  if (tid >= NSIG * NF * 49) {
    int e = tid - NSIG * NF * 49;
    if (e < 7203) ws[OFF_G + e] = 0.f;
    return;
  }
  int g = tid % 49;
  int f = (tid / 49) % NF;
  int sig = tid / (49 * NF);
  int sx = sig / 7, sy = sig % 7;
  int gy = g / 7, gx = g % 7;
  int c = f / 49, rem = f % 49, cy = rem / 7, cx = rem % 7;
  const float4* WT = (const float4*)(ws + OFF_WT);
  const float* V = ws + OFF_V + ((sy * 3 + c) * 224) * 49 + cx * 7 + gx;
  float acc = 0.f;
  for (int y0 = 0; y0 < 32; ++y0) {
    int y = cy * 32 + y0;
    float4 wt = WT[sx * 224 + y];
    int i0 = __float_as_int(wt.z), i1 = __float_as_int(wt.w);
    float w = (gy == i0 ? wt.x : 0.f) + (gy == i1 ? wt.y : 0.f);
    acc = fmaf(w, V[y * 49], acc);
  }
  ws[OFF_T + (sig * 49 + g) * NF + f] = acc * (1.0f / 1024.0f);
}

// fused: F = T2[sig]@g (LDS), h* col + H = F@Wenc one pass, s_i in LDS,
// then per-sample coalesced atomic flush into global G (k-fastest lanes)
__global__ void __launch_bounds__(256) k_H2s(const float* __restrict__ Wenc,
                                             const float* __restrict__ grids,
                                             const int* __restrict__ shx,
                                             const int* __restrict__ shy,
                                             float* __restrict__ ws) {
  __shared__ __align__(16) float sF[NF * NSAMP];  // [f][r]
  __shared__ float sGr[NSAMP * 49];               // [r][g]
  __shared__ float sFeat[NF];
  __shared__ int   sSig[NSAMP];
  __shared__ float sRed[2][NSAMP][4];
  __shared__ float sRedH[4];
  __shared__ float sS[NSAMP];
  int t = threadIdx.x;
  int b = blockIdx.x;
  int i0s = b * NSAMP;
  for (int e = t; e < NSAMP * 49; e += 256) sGr[e] = grids[i0s * 49 + e];
  if (t < NSAMP) sSig[t] = shx[i0s + t] * 7 + shy[i0s + t];
  if (t < NF) sFeat[t] = ws[OFF_FEATS + t];
  __syncthreads();
  for (int idx = t; idx < NF * NSAMP; idx += 256) {
    int r = idx / NF, f = idx - r * NF;
    const float* T2 = ws + OFF_T + sSig[r] * (49 * NF) + f;
    const float* gr = sGr + r * 49;
    float acc = 0.f;
    #pragma unroll
    for (int g = 0; g < 49; ++g) acc = fmaf(T2[g * NF], gr[g], acc);
    sF[f * NSAMP + r] = acc;
  }
  __syncthreads();
  float accA[NSAMP], accB[NSAMP];
  #pragma unroll
  for (int r = 0; r < NSAMP; ++r) { accA[r] = 0.f; accB[r] = 0.f; }
  float h0 = 0.f, h1 = 0.f;
  const float* W0 = Wenc + t;
  const float* W1 = Wenc + t + 256;
  const float4* sF4 = (const float4*)sF;
  for (int f = 0; f < NF; ++f) {
    float w0 = W0[f * ND];
    float w1 = W1[f * ND];
    float fe = sFeat[f];
    h0 = fmaf(fe, w0, h0);
    h1 = fmaf(fe, w1, h1);
    float4 a0 = sF4[f * 3], a1 = sF4[f * 3 + 1], a2 = sF4[f * 3 + 2];
    float a[NSAMP] = {a0.x, a0.y, a0.z, a0.w, a1.x, a1.y, a1.z, a1.w,
                      a2.x, a2.y, a2.z, a2.w};
    #pragma unroll
    for (int r = 0; r < NSAMP; ++r) {
      accA[r] = fmaf(a[r], w0, accA[r]);
      accB[r] = fmaf(a[r], w1, accB[r]);
    }
  }
  int wave = t >> 6, lane = t & 63;
  float hq = h0 * h0 + h1 * h1;
  for (int off = 32; off; off >>= 1) hq += __shfl_down(hq, off);
  if (lane == 0) sRedH[wave] = hq;
  #pragma unroll
  for (int r = 0; r < NSAMP; ++r) {
    float np = accA[r] * h0 + accB[r] * h1;
    float sp = accA[r] * accA[r] + accB[r] * accB[r];
    for (int off = 32; off; off >>= 1) {
      np += __shfl_down(np, off);
      sp += __shfl_down(sp, off);
    }
    if (lane == 0) { sRed[0][r][wave] = np; sRed[1][r][wave] = sp; }
  }
  __syncthreads();
  if (t == 0) sRedH[0] = sqrtf(sRedH[0] + sRedH[1] + sRedH[2] + sRedH[3]);
  __syncthreads();
  if (t < NSAMP) {
    float np = sRed[0][t][0] + sRed[0][t][1] + sRed[0][t][2] + sRed[0][t][3];
    float sp = sRed[1][t][0] + sRed[1][t][1] + sRed[1][t][2] + sRed[1][t][3];
    float den = fmaxf(sRedH[0] * sqrtf(sp), 1e-8f);
    sS[t] = np / den;
  }
  __syncthreads();
  // flush this block's 12 samples into G; lanes map k fastest -> coalesced
  // 49-address runs per (r,p); ~50% of grid entries are zero (skipped)
  for (int e = t; e < NSAMP * 3 * 49; e += 256) {
    int k = e % 49;
    int rp = e / 49;
    int r = rp / 3, p = rp - r * 3;
    float gv = sGr[r * 49 + k];
    if (gv != 0.f) {
      float s = sS[r];
      float add = (p == 0) ? 1.f : ((p == 1) ? s : s * s);
      atomicAdd(&ws[OFF_G + p * 2401 + sSig[r] * 49 + k], add);
    }
  }
}

// per-px-column C slice + final Welford output (one block per px)
__global__ void __launch_bounds__(256) k_CO(const float* __restrict__ ws,
                                            float* __restrict__ out) {
  __shared__ float Gl[3 * 2401];
  __shared__ float sC[NF];          // [k][sx][gy]
  int b = blockIdx.x;               // px
  int t = threadIdx.x;
  for (int e = t; e < 3 * 2401; e += 256) Gl[e] = ws[OFF_G + e];
  __syncthreads();
  const float4* WT = (const float4*)(ws + OFF_WT);
  if (t < NF) {
    int k = t / 49, r = t - k * 49;
    int sx = r / 7, gy = r % 7;
    float acc = 0.f;
    for (int sy = 0; sy < 7; ++sy) {
      float4 wt = WT[sy * 224 + b];
      int i0 = __float_as_int(wt.z), i1 = __float_as_int(wt.w);
      int base = k * 2401 + (sx * 7 + sy) * 49 + gy * 7;
      acc += wt.x * Gl[base + i0] + wt.y * Gl[base + i1];
    }
    sC[t] = acc;
  }
  __syncthreads();
  if (t < 224) {
    int py = t;
    float S0 = 0.f, S1 = 0.f, S2 = 0.f;
    for (int sx = 0; sx < 7; ++sx) {
      float4 wt = WT[sx * 224 + py];
      int i0 = __float_as_int(wt.z), i1 = __float_as_int(wt.w);
      int base = sx * 7;
      S0 += wt.x * sC[base + i0]      + wt.y * sC[base + i1];
      S1 += wt.x * sC[49 + base + i0] + wt.y * sC[49 + base + i1];
      S2 += wt.x * sC[98 + base + i0] + wt.y * sC[98 + base + i1];
    }
    float W = 1e-10f + S0;
    float R = S1 / W;
    float U = S2 - S1 * S1 / W;
    out[py * 224 + b] = R;
    out[224 * 224 + py * 224 + b] = U / (W - 1.0f);
  }
}

extern "C" void kernel_launch(void* const* d_in, const int* in_sizes, int n_in,
                              void* d_out, int out_size, void* d_ws, size_t ws_size,
                              hipStream_t stream) {
  const float* x     = (const float*)d_in[0];
  const float* Wenc  = (const float*)d_in[1];
  const float* grids = (const float*)d_in[2];
  const int*   shx   = (const int*)d_in[3];
  const int*   shy   = (const int*)d_in[4];
  float* out = (float*)d_out;
  float* ws  = (float*)d_ws;

  int vblocks = (7 * 3 * 224 * 7 + 255) / 256;           // 129
  k_initV<<<NF + 1 + vblocks, 256, 0, stream>>>(x, ws);  // 277 blocks
  // 1379 work blocks + tail threads for G zeroing
  k_T<<<(NSIG * NF * 49 + 7203 + 255) / 256, 256, 0, stream>>>(ws);
  k_H2s<<<NHBLK, 256, 0, stream>>>(Wenc, grids, shx, shy, ws);
  k_CO<<<224, 256, 0, stream>>>(ws, out);
}